// Round 12
// baseline (4131.555 us; speedup 1.0000x reference)
//
#include <hip/hip_runtime.h>
#include <math.h>

typedef unsigned int u32;

// ---- output element offsets (d_out is FLOAT32, 101760 elements) ----
#define OUT_ZS    0        // z_smooth [3][127][10]
#define OUT_PS    3810     // P_smooth [3][127][100]
#define OUT_AALL  41910    // a_all    [3][128][5]
#define OUT_A     43830    // A        [128][3][100]
#define OUT_C     82230    // C        [128][3][50]
#define OUT_LASTZ 101430   // last_z   [3][10]
#define OUT_LASTP 101460   // last_P   [3][100]

__device__ __forceinline__ float sigm(float x){ return 1.f/(1.f+expf(-x)); }
__device__ __forceinline__ float safed(float d){
    return (fabsf(d) < 1e-30f) ? ((d < 0.f) ? -1e-30f : 1e-30f) : d;
}

// ---- static device workspace ----
__device__ float r12_c1[25165824];   // conv1 out, planar [f*8+og][1024 pix][8ch]
__device__ float r12_c2[12582912];   // [384][256][128] NHWC
__device__ float r12_c3[12582912];   // [384][64][512] NHWC
__device__ float r12_wdT[163840];    // [5][32768] transposed wd cols 0..4
__device__ float r12_hs[49152];      // [128][3][128]
__device__ float r12_zhat[3840];     // [128][3][10]
__device__ float r12_phat[38400];    // [128][3][100] (clamped)
__device__ float r12_pz[3840];
__device__ float r12_pp[38400];
__device__ float r12_aall[1920];     // [3][128][5]
__device__ float r12_A[38400];       // [128][3][100]
__device__ float r12_C[19200];       // [128][3][50]
__device__ float r12_G[38400];       // [128][3][100]  A^T @ inv(phat)

// ============================ conv1 (tiled) ============================
__global__ __launch_bounds__(256) void conv1_r12(const float* __restrict__ img,
        const float* __restrict__ w1, const float* __restrict__ b1, float* __restrict__ out)
{
    __shared__ float in_lds[66*66];
    const int f = blockIdx.x, tid = threadIdx.x;
    const int og = tid >> 5, sg = tid & 31;

    for (int i = tid; i < 66*66; i += 256) in_lds[i] = 0.f;
    __syncthreads();
    const float4* src = (const float4*)(img + f*4096);
    for (int i = tid; i < 1024; i += 256) {
        int r = i >> 4, c0 = (i & 15) * 4;
        float4 v = src[i];
        float* dst = &in_lds[(r+1)*66 + c0 + 1];
        dst[0]=v.x; dst[1]=v.y; dst[2]=v.z; dst[3]=v.w;
    }
    float wr[16][8];
    #pragma unroll
    for (int k = 0; k < 16; k++) {
        float4 a = *(const float4*)&w1[k*64 + og*8];
        float4 b = *(const float4*)&w1[k*64 + og*8 + 4];
        wr[k][0]=a.x; wr[k][1]=a.y; wr[k][2]=a.z; wr[k][3]=a.w;
        wr[k][4]=b.x; wr[k][5]=b.y; wr[k][6]=b.z; wr[k][7]=b.w;
    }
    float bias[8];
    #pragma unroll
    for (int j = 0; j < 8; j++) bias[j] = b1[og*8+j];
    __syncthreads();

    float* obase = out + (f*8 + og)*8192;
    for (int yy = 0; yy < 32; yy++) {
        float inv[16];
        #pragma unroll
        for (int ky = 0; ky < 4; ky++)
            #pragma unroll
            for (int kx = 0; kx < 4; kx++)
                inv[ky*4+kx] = in_lds[(2*yy+ky)*66 + 2*sg+kx];
        float acc[8];
        #pragma unroll
        for (int j = 0; j < 8; j++) acc[j] = bias[j];
        #pragma unroll
        for (int k = 0; k < 16; k++)
            #pragma unroll
            for (int j = 0; j < 8; j++) acc[j] += inv[k]*wr[k][j];
        #pragma unroll
        for (int j = 0; j < 8; j++) acc[j] = fmaxf(acc[j], 0.f);
        float* op = obase + (yy*32+sg)*8;
        *(float4*)(op)   = make_float4(acc[0],acc[1],acc[2],acc[3]);
        *(float4*)(op+4) = make_float4(acc[4],acc[5],acc[6],acc[7]);
    }
}

// ============================ conv2 (tiled, og-fast lanes) ============================
// in: conv1out planar [f][8][1024][8]; w2 [16][64][128]; out: [f][256][128] NHWC
__global__ __launch_bounds__(256) void conv2_r12(const float* __restrict__ c1,
        const float* __restrict__ w2, const float* __restrict__ b2, float* __restrict__ outp)
{
    __shared__ float in_lds[34*34*8];   // 36,992 B
    const int f = blockIdx.x, ocg = blockIdx.y, tid = threadIdx.x;
    // og fast (tid&7): fragment addr depends on sg only -> 8-lane LDS broadcast,
    // 8 distinct addrs/wave at 16-float stride = 4-way conflict (was 8-way).
    const int og = tid & 7, sg = tid >> 3;
    const int oc0 = ocg*64 + og*8;

    float acc[8][8];
    #pragma unroll
    for (int s = 0; s < 8; s++)
        #pragma unroll
        for (int j = 0; j < 8; j++) acc[s][j] = b2[oc0+j];

    for (int i = tid; i < 34*34*8; i += 256) in_lds[i] = 0.f;
    __syncthreads();

    for (int icg = 0; icg < 8; icg++) {
        const float4* gsrc = (const float4*)(c1 + (f*8 + icg)*8192);
        for (int i = tid; i < 2048; i += 256) {
            int y = i >> 6, r = i & 63;
            ((float4*)&in_lds[((y+1)*34 + 1)*8])[r] = gsrc[i];
        }
        __syncthreads();
        for (int kk = 0; kk < 16; kk++) {
            const int ky = kk >> 2, kx = kk & 3;
            float wr[8][8];
            #pragma unroll
            for (int i2 = 0; i2 < 8; i2++) {
                const float* wp = w2 + (kk*64 + icg*8 + i2)*128 + oc0;
                float4 a = *(const float4*)wp;
                float4 b = *(const float4*)(wp+4);
                wr[i2][0]=a.x; wr[i2][1]=a.y; wr[i2][2]=a.z; wr[i2][3]=a.w;
                wr[i2][4]=b.x; wr[i2][5]=b.y; wr[i2][6]=b.z; wr[i2][7]=b.w;
            }
            #pragma unroll
            for (int s = 0; s < 8; s++) {
                const int id = s*32 + sg, y = id >> 4, x = id & 15;
                const float* ip = &in_lds[((2*y+ky)*34 + (2*x+kx))*8];
                float4 pa = *(const float4*)ip;
                float4 pb = *(const float4*)(ip+4);
                #pragma unroll
                for (int j = 0; j < 8; j++)
                    acc[s][j] += pa.x*wr[0][j] + pa.y*wr[1][j] + pa.z*wr[2][j] + pa.w*wr[3][j]
                               + pb.x*wr[4][j] + pb.y*wr[5][j] + pb.z*wr[6][j] + pb.w*wr[7][j];
            }
        }
        __syncthreads();
    }
    float* ob = outp + f*32768 + oc0;
    #pragma unroll
    for (int s = 0; s < 8; s++) {
        const int id = s*32 + sg, y = id >> 4, x = id & 15;
        float* op = ob + (y*16+x)*128;
        *(float4*)(op)   = make_float4(fmaxf(acc[s][0],0.f), fmaxf(acc[s][1],0.f),
                                       fmaxf(acc[s][2],0.f), fmaxf(acc[s][3],0.f));
        *(float4*)(op+4) = make_float4(fmaxf(acc[s][4],0.f), fmaxf(acc[s][5],0.f),
                                       fmaxf(acc[s][6],0.f), fmaxf(acc[s][7],0.f));
    }
}

// ============================ conv3 (tiled, og-fast lanes) ============================
// in: conv2out [f][256][128] NHWC; w3 [16][128][512]; out: [f][64][512] NHWC
__global__ __launch_bounds__(256) void conv3_r12(const float* __restrict__ c2,
        const float* __restrict__ w3, const float* __restrict__ b3, float* __restrict__ outp)
{
    __shared__ float in_lds[18*18*32];   // 41,472 B
    const int f = blockIdx.x, ocg = blockIdx.y, tid = threadIdx.x;
    // og fast (tid&31): wave = 32 og (LDS broadcast) x 2 sg (stride 64 floats ->
    // 2 addrs on one bank quad = 2-way = free). Was sg-fast: 8-way conflict, 3.5e8 cycles.
    const int og = tid & 31, sg = tid >> 5;
    const int oc0 = ocg*256 + og*8;

    float acc[8][8];
    #pragma unroll
    for (int s = 0; s < 8; s++)
        #pragma unroll
        for (int j = 0; j < 8; j++) acc[s][j] = b3[oc0+j];

    for (int i = tid; i < 18*18*32; i += 256) in_lds[i] = 0.f;
    __syncthreads();

    for (int ich = 0; ich < 4; ich++) {
        for (int i = tid; i < 2048; i += 256) {
            int pix = i >> 3, q = i & 7;
            int y = pix >> 4, x = pix & 15;
            ((float4*)&in_lds[((y+1)*18 + (x+1))*32])[q] =
                ((const float4*)(c2 + f*32768 + pix*128 + ich*32))[q];
        }
        __syncthreads();
        for (int kk = 0; kk < 16; kk++) {
            const int ky = kk >> 2, kx = kk & 3;
            for (int icb = 0; icb < 4; icb++) {
                float wr[8][8];
                #pragma unroll
                for (int i2 = 0; i2 < 8; i2++) {
                    const float* wp = w3 + (kk*128 + ich*32 + icb*8 + i2)*512 + oc0;
                    float4 a = *(const float4*)wp;
                    float4 b = *(const float4*)(wp+4);
                    wr[i2][0]=a.x; wr[i2][1]=a.y; wr[i2][2]=a.z; wr[i2][3]=a.w;
                    wr[i2][4]=b.x; wr[i2][5]=b.y; wr[i2][6]=b.z; wr[i2][7]=b.w;
                }
                #pragma unroll
                for (int s = 0; s < 8; s++) {
                    const float* ip = &in_lds[((2*s+ky)*18 + (2*sg+kx))*32 + icb*8];
                    float4 pa = *(const float4*)ip;
                    float4 pb = *(const float4*)(ip+4);
                    #pragma unroll
                    for (int j = 0; j < 8; j++)
                        acc[s][j] += pa.x*wr[0][j] + pa.y*wr[1][j] + pa.z*wr[2][j] + pa.w*wr[3][j]
                                   + pb.x*wr[4][j] + pb.y*wr[5][j] + pb.z*wr[6][j] + pb.w*wr[7][j];
                }
            }
        }
        __syncthreads();
    }
    float* ob = outp + f*32768 + oc0;
    #pragma unroll
    for (int s = 0; s < 8; s++) {
        float* op = ob + (s*8+sg)*512;
        *(float4*)(op)   = make_float4(fmaxf(acc[s][0],0.f), fmaxf(acc[s][1],0.f),
                                       fmaxf(acc[s][2],0.f), fmaxf(acc[s][3],0.f));
        *(float4*)(op+4) = make_float4(fmaxf(acc[s][4],0.f), fmaxf(acc[s][5],0.f),
                                       fmaxf(acc[s][6],0.f), fmaxf(acc[s][7],0.f));
    }
}

// ============================ wd transpose (cols 0..4) ============================
__global__ __launch_bounds__(256) void wdt_r12(const float* __restrict__ wd, float* __restrict__ wdT)
{
    int idx = blockIdx.x*256 + threadIdx.x;
    if (idx < 163840) {
        int j = idx & 32767, d = idx >> 15;
        wdT[d*32768 + j] = wd[j*20 + d];
    }
}

// ============================ dense -> a_all (transposed wd, float4) ============================
__global__ __launch_bounds__(256) void dense_r12(const float* __restrict__ bd,
        float* __restrict__ dout)
{
    const int f = blockIdx.x, tid = threadIdx.x;
    float p0=0,p1=0,p2=0,p3=0,p4=0;
    const float4* x4 = (const float4*)(r12_c3 + f*32768);
    for (int j = tid; j < 8192; j += 256) {
        float4 v = x4[j];
        float4 w0 = *(const float4*)&r12_wdT[          4*j];
        float4 w1 = *(const float4*)&r12_wdT[32768   + 4*j];
        float4 w2 = *(const float4*)&r12_wdT[65536   + 4*j];
        float4 w3 = *(const float4*)&r12_wdT[98304   + 4*j];
        float4 w4 = *(const float4*)&r12_wdT[131072  + 4*j];
        p0 += v.x*w0.x + v.y*w0.y + v.z*w0.z + v.w*w0.w;
        p1 += v.x*w1.x + v.y*w1.y + v.z*w1.z + v.w*w1.w;
        p2 += v.x*w2.x + v.y*w2.y + v.z*w2.z + v.w*w2.w;
        p3 += v.x*w3.x + v.y*w3.y + v.z*w3.z + v.w*w3.w;
        p4 += v.x*w4.x + v.y*w4.y + v.z*w4.z + v.w*w4.w;
    }
    __shared__ float red[5][256];
    red[0][tid]=p0; red[1][tid]=p1; red[2][tid]=p2; red[3][tid]=p3; red[4][tid]=p4;
    __syncthreads();
    for (int st = 128; st > 0; st >>= 1) {
        if (tid < st) {
            #pragma unroll
            for (int d = 0; d < 5; d++) red[d][tid] += red[d][tid+st];
        }
        __syncthreads();
    }
    if (tid < 5) {
        float v = red[tid][0] + bd[tid];
        r12_aall[f*5 + tid] = v;
        dout[OUT_AALL + f*5 + tid] = v;
    }
}

// ============================ LSTM ============================
__global__ __launch_bounds__(128) void lstm_r12(const float* __restrict__ lk,
        const float* __restrict__ lrk, const float* __restrict__ lb)
{
    const int b = blockIdx.x, c = threadIdx.x;
    __shared__ float h[128];
    __shared__ float a[5];
    h[c] = 0.f;
    float cs = 0.f;
    __syncthreads();
    for (int t = 0; t < 128; t++) {
        if (c < 5) a[c] = (t == 0) ? 0.f : r12_aall[(b*128 + (t-1))*5 + c];
        __syncthreads();
        float g[4];
        #pragma unroll
        for (int q = 0; q < 4; q++) {
            int col = q*128 + c;
            float s = lb[col];
            for (int d = 0; d < 5; d++)   s += a[d] * lk[d*512 + col];
            for (int j = 0; j < 128; j++) s += h[j] * lrk[j*512 + col];
            g[q] = s;
        }
        __syncthreads();
        float gi = g[0], gf = g[1], gg = g[2], go = g[3];
        cs = sigm(gf)*cs + sigm(gi)*tanhf(gg);
        float hn = sigm(go)*tanhf(cs);
        h[c] = hn;
        r12_hs[(t*3 + b)*128 + c] = hn;
        __syncthreads();
    }
}

// ============================ abc -> A, C ============================
__global__ __launch_bounds__(192) void abc_r12(const float* __restrict__ wabc,
        const float* __restrict__ babc, float* __restrict__ dout)
{
    const int tb = blockIdx.x, c = threadIdx.x;
    __shared__ float h_lds[128];
    if (c < 128) h_lds[c] = r12_hs[tb*128 + c];
    __syncthreads();
    if (c < 150) {
        float s = babc[c];
        for (int j = 0; j < 128; j++) s += h_lds[j]*wabc[j*150 + c];
        if (c < 100) { r12_A[tb*100 + c] = s; dout[OUT_A + tb*100 + c] = s; }
        else         { r12_C[tb*50 + (c-100)] = s; dout[OUT_C + tb*50 + (c-100)] = s; }
    }
}

// ============================ Kalman filter ============================
__global__ __launch_bounds__(128) void kf_r12(float* __restrict__ dout)
{
    const int b = blockIdx.x, tid = threadIdx.x;
    const int i10 = tid/10, j10 = tid%10;
    __shared__ float A[100], C[50], z[10], P[100], zh[10], AP[100], Ph[100],
                     resid[5], CPm[50], Sa[5][11], PCt[50], K[50], pzv[10], Pn[100], av[5];
    if (tid < 100) P[tid] = (i10==j10) ? 1.f : 0.f;
    if (tid < 10) z[tid] = 0.f;
    for (int t = 0; t < 128; t++) {
        __syncthreads();
        if (tid < 100) A[tid] = r12_A[(t*3+b)*100 + tid];
        if (tid < 50)  C[tid] = r12_C[(t*3+b)*50 + tid];
        if (tid < 5)   av[tid] = r12_aall[(b*128+t)*5 + tid];
        __syncthreads();
        if (tid < 10) { float s=0.f; for (int k=0;k<10;k++) s += A[tid*10+k]*z[k]; zh[tid]=s; }
        if (tid < 100){ float s=0.f; for (int k=0;k<10;k++) s += A[i10*10+k]*P[k*10+j10]; AP[tid]=s; }
        __syncthreads();
        if (tid < 100){ float s=(i10==j10)?0.08f:0.f; for (int k=0;k<10;k++) s += AP[i10*10+k]*A[j10*10+k]; Ph[tid]=s; }
        __syncthreads();
        if (tid < 5)  { float s=av[tid]; for (int k=0;k<10;k++) s -= C[tid*10+k]*zh[k]; resid[tid]=s; }
        if (tid < 50) { int i=tid/10, j=tid%10; float s=0.f; for (int k=0;k<10;k++) s += C[i*10+k]*Ph[k*10+j]; CPm[tid]=s; }
        __syncthreads();
        if (tid < 25) { int i=tid/5, j=tid%5; float s=(i==j)?0.03f:0.f; for (int k=0;k<10;k++) s += CPm[i*10+k]*C[j*10+k]; Sa[i][j]=s; }
        if (tid >= 32 && tid < 57) { int q=tid-32, i=q/5, j=q%5; Sa[i][5+j] = (i==j)?1.f:0.f; }
        if (tid >= 64 && tid < 114){ int q=tid-64, i=q/5, j=q%5; float s=0.f; for (int k=0;k<10;k++) s += Ph[i*10+k]*C[j*10+k]; PCt[q]=s; }
        __syncthreads();
        for (int k = 0; k < 5; k++) {
            const int r = tid/10, cc = tid%10;
            float pinv = 1.f/safed(Sa[k][k]);
            float myf = 0.f, rowv = 0.f;
            if (tid < 50) { myf = Sa[r][k]; rowv = Sa[k][cc]; }
            __syncthreads();
            if (tid < 50) {
                if (r == k) Sa[k][cc] = rowv * pinv;
                else        Sa[r][cc] -= myf * pinv * rowv;
            }
            __syncthreads();
        }
        if (tid < 50) { int i=tid/5, j=tid%5; float s=0.f; for (int k=0;k<5;k++) s += PCt[i*5+k]*Sa[k][5+j]; K[tid]=s; }
        __syncthreads();
        if (tid < 10) { float s=zh[tid]; for (int k=0;k<5;k++) s += K[tid*5+k]*resid[k]; pzv[tid]=s; }
        if (tid < 100){ float s=0.f; for (int k=0;k<5;k++) s += K[i10*5+k]*C[k*10+j10]; AP[tid]=s; }  // AP := K@C
        __syncthreads();
        if (tid < 100){ float s=Ph[tid]; for (int k=0;k<10;k++) s -= AP[i10*10+k]*Ph[k*10+j10]; Pn[tid]=s; }
        __syncthreads();
        if (tid < 10) { r12_zhat[(t*3+b)*10+tid]=zh[tid]; r12_pz[(t*3+b)*10+tid]=pzv[tid]; z[tid]=pzv[tid]; }
        if (tid < 100){
            float phc = fmaxf(Ph[tid], (i10==j10)?1e-4f:0.f);   // elementwise max with 1e-4*I
            r12_phat[(t*3+b)*100+tid]=phc;
            r12_pp[(t*3+b)*100+tid]=Pn[tid];
            P[tid]=Pn[tid];
        }
    }
    __syncthreads();
    if (tid < 10)  dout[OUT_LASTZ + b*10 + tid]  = z[tid];
    if (tid < 100) dout[OUT_LASTP + b*100 + tid] = P[tid];
}

// ============================ G = A^T @ inv(Phat_clamped) ============================
__global__ __launch_bounds__(256) void ginv_r12()
{
    const int idx = blockIdx.x;
    const int tt = idx/3 + 1, b = idx%3;   // tt in 1..127
    const int tid = threadIdx.x;
    __shared__ float M[10][21];
    __shared__ float A[100];
    __shared__ int piv;
    if (tid < 100) {
        int i = tid/10, j = tid%10;
        M[i][j] = r12_phat[(tt*3+b)*100 + tid];
        M[i][10+j] = (i==j) ? 1.f : 0.f;
        A[tid] = r12_A[(tt*3+b)*100 + tid];
    }
    __syncthreads();
    const int r = tid/20, cc = tid%20;
    for (int k = 0; k < 10; k++) {
        if (tid == 0) {
            int p = k; float best = fabsf(M[k][k]);
            for (int rr = k+1; rr < 10; rr++) {
                float v = fabsf(M[rr][k]);
                if (v > best) { best = v; p = rr; }
            }
            piv = p;
        }
        __syncthreads();
        if (piv != k && tid < 20) {
            float a = M[k][tid], bb = M[piv][tid];
            M[k][tid] = bb; M[piv][tid] = a;
        }
        __syncthreads();
        float pinv = 1.f/safed(M[k][k]);
        float myf = 0.f, rowv = 0.f;
        if (tid < 200) { myf = M[r][k]; rowv = M[k][cc]; }
        __syncthreads();
        if (tid < 200) {
            if (r == k) M[k][cc] = rowv*pinv;
            else        M[r][cc] -= myf*pinv*rowv;
        }
        __syncthreads();
    }
    if (tid < 100) {
        int i = tid/10, j = tid%10;
        float s = 0.f;
        #pragma unroll
        for (int k = 0; k < 10; k++) s += A[k*10+i]*M[k][10+j];
        r12_G[(tt*3+b)*100 + tid] = s;
    }
}

// ============================ RTS smoother ============================
__global__ __launch_bounds__(128) void rts_r12(float* __restrict__ dout)
{
    const int b = blockIdx.x, tid = threadIdx.x;
    const int i10 = tid/10, j10 = tid%10;
    __shared__ float zc[10], Pc[100], D[100], Gt[100], pPm[100], ph[100],
                     zh[10], pzv[10], dz[10], T1[100], zn[10], Pnn[100];
    if (tid < 10)  zc[tid] = r12_pz[(127*3+b)*10 + tid];
    if (tid < 100) Pc[tid] = r12_pp[(127*3+b)*100 + tid];
    for (int t = 126; t >= 0; t--) {
        __syncthreads();
        if (tid < 100) {
            Gt[tid]  = r12_G[((t+1)*3+b)*100 + tid];
            pPm[tid] = r12_pp[(t*3+b)*100 + tid];
            ph[tid]  = r12_phat[((t+1)*3+b)*100 + tid];
        }
        if (tid < 10) {
            zh[tid]  = r12_zhat[((t+1)*3+b)*10 + tid];
            pzv[tid] = r12_pz[(t*3+b)*10 + tid];
        }
        __syncthreads();
        if (tid < 100){ float s=0.f; for (int k=0;k<10;k++) s += pPm[i10*10+k]*Gt[k*10+j10]; D[tid]=s; }
        if (tid < 10) dz[tid] = zc[tid] - zh[tid];
        __syncthreads();
        if (tid < 10) { float s=pzv[tid]; for (int k=0;k<10;k++) s += D[tid*10+k]*dz[k]; zn[tid]=s; }
        if (tid < 100){ float s=0.f; for (int k=0;k<10;k++) s += D[i10*10+k]*(Pc[k*10+j10]-ph[k*10+j10]); T1[tid]=s; }
        __syncthreads();
        if (tid < 100){ float s=pPm[tid]; for (int k=0;k<10;k++) s += T1[i10*10+k]*D[j10*10+k]; Pnn[tid]=s; }
        __syncthreads();
        if (tid < 10) { dout[OUT_ZS + (b*127+t)*10 + tid] = zn[tid]; zc[tid]=zn[tid]; }
        if (tid < 100){ dout[OUT_PS + (b*127+t)*100 + tid] = Pnn[tid]; Pc[tid]=Pnn[tid]; }
    }
}

// ============================ launch ============================
extern "C" void kernel_launch(void* const* d_in, const int* in_sizes, int n_in,
                              void* d_out, int out_size, void* d_ws, size_t ws_size,
                              hipStream_t stream)
{
    (void)in_sizes; (void)n_in; (void)out_size; (void)d_ws; (void)ws_size;
    const float* images = (const float*)d_in[0];
    const float* w1   = (const float*)d_in[1];
    const float* b1   = (const float*)d_in[2];
    const float* w2   = (const float*)d_in[3];
    const float* b2   = (const float*)d_in[4];
    const float* w3   = (const float*)d_in[5];
    const float* b3   = (const float*)d_in[6];
    const float* wd   = (const float*)d_in[7];
    const float* bd   = (const float*)d_in[8];
    const float* lk   = (const float*)d_in[9];
    const float* lrk  = (const float*)d_in[10];
    const float* lb   = (const float*)d_in[11];
    const float* wabc = (const float*)d_in[12];
    const float* babc = (const float*)d_in[13];
    float* dout = (float*)d_out;   // d_out is FLOAT32 (verified R10)

    float *c1p, *c2p, *c3p, *wdTp;
    hipGetSymbolAddress((void**)&c1p, HIP_SYMBOL(r12_c1));
    hipGetSymbolAddress((void**)&c2p, HIP_SYMBOL(r12_c2));
    hipGetSymbolAddress((void**)&c3p, HIP_SYMBOL(r12_c3));
    hipGetSymbolAddress((void**)&wdTp, HIP_SYMBOL(r12_wdT));

    conv1_r12<<<dim3(384), dim3(256), 0, stream>>>(images, w1, b1, c1p);
    wdt_r12<<<dim3(640), dim3(256), 0, stream>>>(wd, wdTp);
    conv2_r12<<<dim3(384,2), dim3(256), 0, stream>>>(c1p, w2, b2, c2p);
    conv3_r12<<<dim3(384,2), dim3(256), 0, stream>>>(c2p, w3, b3, c3p);
    dense_r12<<<dim3(384), dim3(256), 0, stream>>>(bd, dout);
    lstm_r12<<<dim3(3), dim3(128), 0, stream>>>(lk, lrk, lb);
    abc_r12<<<dim3(384), dim3(192), 0, stream>>>(wabc, babc, dout);
    kf_r12<<<dim3(3), dim3(128), 0, stream>>>(dout);
    ginv_r12<<<dim3(381), dim3(256), 0, stream>>>();
    rts_r12<<<dim3(3), dim3(128), 0, stream>>>(dout);
}

// Round 13
// 1959.712 us; speedup vs baseline: 2.1082x; 2.1082x over previous
//
#include <hip/hip_runtime.h>
#include <math.h>

typedef unsigned int   u32;
typedef unsigned short u16;
typedef short bf16x8 __attribute__((ext_vector_type(8)));
typedef float f32x4  __attribute__((ext_vector_type(4)));

// ---- output element offsets (d_out is FLOAT32, 101760 elements) ----
#define OUT_ZS    0
#define OUT_PS    3810
#define OUT_AALL  41910
#define OUT_A     43830
#define OUT_C     82230
#define OUT_LASTZ 101430
#define OUT_LASTP 101460

__device__ __forceinline__ float sigm(float x){ return 1.f/(1.f+expf(-x)); }
__device__ __forceinline__ float safed(float d){
    return (fabsf(d) < 1e-30f) ? ((d < 0.f) ? -1e-30f : 1e-30f) : d;
}
__device__ __forceinline__ u16 f2b(float f) {
    union { float f; u32 u; } v; v.f = f;
    u32 r = v.u + 0x7fffu + ((v.u >> 16) & 1u);   // RNE
    return (u16)(r >> 16);
}
__device__ __forceinline__ float b2f(u16 u) {
    union { u32 x; float f; } v; v.x = ((u32)u) << 16; return v.f;
}
__device__ __forceinline__ u32 packb(float a, float b){ return (u32)f2b(a) | ((u32)f2b(b) << 16); }

// ---- static device workspace ----
__device__ u16   r13_c1[25165824];   // conv1 out bf16 NHWC [384][32][32][64]
__device__ u16   r13_c2[12582912];   // conv2 out bf16 NHWC [384][16][16][128]
__device__ float r13_c3[12582912];   // conv3 out fp32 NHWC [384][8][8][512]
__device__ u16   r13_w2h[131072];    // w2T hi bf16 [128 oc][1024 k]
__device__ u16   r13_w2l[131072];    // w2T lo bf16
__device__ u16   r13_w3h[1048576];   // w3T hi bf16 [512 oc][2048 k]
__device__ u16   r13_w3l[1048576];   // w3T lo bf16
__device__ float r13_wdT[163840];    // [5][32768]
__device__ float r13_hs[49152];
__device__ float r13_zhat[3840];
__device__ float r13_phat[38400];
__device__ float r13_pz[3840];
__device__ float r13_pp[38400];
__device__ float r13_aall[1920];
__device__ float r13_A[38400];
__device__ float r13_C[19200];
__device__ float r13_G[38400];

// ============================ conv1 (fp32 VALU, bf16 NHWC out) ============================
__global__ __launch_bounds__(256) void conv1_r13(const float* __restrict__ img,
        const float* __restrict__ w1, const float* __restrict__ b1, u16* __restrict__ out)
{
    __shared__ float in_lds[66*66];
    const int f = blockIdx.x, tid = threadIdx.x;
    const int og = tid >> 5, sg = tid & 31;

    for (int i = tid; i < 66*66; i += 256) in_lds[i] = 0.f;
    __syncthreads();
    const float4* src = (const float4*)(img + f*4096);
    for (int i = tid; i < 1024; i += 256) {
        int r = i >> 4, c0 = (i & 15) * 4;
        float4 v = src[i];
        float* dst = &in_lds[(r+1)*66 + c0 + 1];
        dst[0]=v.x; dst[1]=v.y; dst[2]=v.z; dst[3]=v.w;
    }
    float wr[16][8];
    #pragma unroll
    for (int k = 0; k < 16; k++) {
        float4 a = *(const float4*)&w1[k*64 + og*8];
        float4 b = *(const float4*)&w1[k*64 + og*8 + 4];
        wr[k][0]=a.x; wr[k][1]=a.y; wr[k][2]=a.z; wr[k][3]=a.w;
        wr[k][4]=b.x; wr[k][5]=b.y; wr[k][6]=b.z; wr[k][7]=b.w;
    }
    float bias[8];
    #pragma unroll
    for (int j = 0; j < 8; j++) bias[j] = b1[og*8+j];
    __syncthreads();

    for (int yy = 0; yy < 32; yy++) {
        float inv[16];
        #pragma unroll
        for (int ky = 0; ky < 4; ky++)
            #pragma unroll
            for (int kx = 0; kx < 4; kx++)
                inv[ky*4+kx] = in_lds[(2*yy+ky)*66 + 2*sg+kx];
        float acc[8];
        #pragma unroll
        for (int j = 0; j < 8; j++) acc[j] = bias[j];
        #pragma unroll
        for (int k = 0; k < 16; k++)
            #pragma unroll
            for (int j = 0; j < 8; j++) acc[j] += inv[k]*wr[k][j];
        #pragma unroll
        for (int j = 0; j < 8; j++) acc[j] = fmaxf(acc[j], 0.f);
        uint4 pk = make_uint4(packb(acc[0],acc[1]), packb(acc[2],acc[3]),
                              packb(acc[4],acc[5]), packb(acc[6],acc[7]));
        *(uint4*)(out + (f*1024 + yy*32 + sg)*64 + og*8) = pk;
    }
}

// ============================ weight transpose + bf16 split ============================
__global__ __launch_bounds__(256) void w2t_r13(const float* __restrict__ w2,
        u16* __restrict__ hi, u16* __restrict__ lo)
{
    int idx = blockIdx.x*256 + threadIdx.x;
    if (idx < 131072) {
        int k = idx >> 7, oc = idx & 127;       // w2 flat [1024 k][128 oc]
        float v = w2[idx];
        u16 h = f2b(v);
        hi[oc*1024 + k] = h;
        lo[oc*1024 + k] = f2b(v - b2f(h));
    }
}
__global__ __launch_bounds__(256) void w3t_r13(const float* __restrict__ w3,
        u16* __restrict__ hi, u16* __restrict__ lo)
{
    int idx = blockIdx.x*256 + threadIdx.x;
    if (idx < 1048576) {
        int k = idx >> 9, oc = idx & 511;       // w3 flat [2048 k][512 oc]
        float v = w3[idx];
        u16 h = f2b(v);
        hi[oc*2048 + k] = h;
        lo[oc*2048 + k] = f2b(v - b2f(h));
    }
}
__global__ __launch_bounds__(256) void wdt_r13(const float* __restrict__ wd, float* __restrict__ wdT)
{
    int idx = blockIdx.x*256 + threadIdx.x;
    if (idx < 163840) {
        int j = idx & 32767, d = idx >> 15;
        wdT[d*32768 + j] = wd[j*20 + d];
    }
}

// ============================ conv2 MFMA (bf16, split-B) ============================
// GEMM per (f, mc): M=128 out-pixels, N=128 oc, K=1024 (16 kk x 64 ic)
__global__ __launch_bounds__(256) void conv2_r13(const u16* __restrict__ c1b,
        const u16* __restrict__ w2h, const u16* __restrict__ w2l,
        const float* __restrict__ b2, u16* __restrict__ c2b)
{
    __shared__ __align__(16) u16 slab[128*72];   // [pix][64 ic + 8 pad]
    const int f = blockIdx.x, mc = blockIdx.y, tid = threadIdx.x;
    const int wave = tid >> 6, lane = tid & 63, quad = lane >> 4, ln = lane & 15;

    f32x4 acc[8][2];
    const f32x4 zz = {0.f, 0.f, 0.f, 0.f};
    #pragma unroll
    for (int mt = 0; mt < 8; mt++) { acc[mt][0] = zz; acc[mt][1] = zz; }

    const int sp = tid >> 1;               // staging pixel 0..127
    const int sy = mc*8 + (sp >> 4), sx = sp & 15;
    const int sic = (tid & 1) * 32;

    for (int kk = 0; kk < 16; kk++) {
        const int ky = kk >> 2, kx = kk & 3;
        __syncthreads();
        {
            int iy = 2*sy - 1 + ky, ix = 2*sx - 1 + kx;
            uint4* d4 = (uint4*)&slab[sp*72 + sic];
            if (iy >= 0 && iy < 32 && ix >= 0 && ix < 32) {
                const uint4* s4 = (const uint4*)&c1b[((f*32 + iy)*32 + ix)*64 + sic];
                d4[0]=s4[0]; d4[1]=s4[1]; d4[2]=s4[2]; d4[3]=s4[3];
            } else {
                uint4 z = make_uint4(0,0,0,0);
                d4[0]=z; d4[1]=z; d4[2]=z; d4[3]=z;
            }
        }
        __syncthreads();
        #pragma unroll
        for (int ks = 0; ks < 2; ks++) {
            bf16x8 af[8];
            #pragma unroll
            for (int mt = 0; mt < 8; mt++)
                af[mt] = *(const bf16x8*)&slab[(mt*16 + ln)*72 + ks*32 + quad*8];
            #pragma unroll
            for (int nt = 0; nt < 2; nt++) {
                const int oc = wave*32 + nt*16 + ln;
                const int kb = kk*64 + ks*32 + quad*8;
                bf16x8 bh = *(const bf16x8*)&w2h[oc*1024 + kb];
                bf16x8 bl = *(const bf16x8*)&w2l[oc*1024 + kb];
                #pragma unroll
                for (int mt = 0; mt < 8; mt++) {
                    acc[mt][nt] = __builtin_amdgcn_mfma_f32_16x16x32_bf16(af[mt], bh, acc[mt][nt], 0,0,0);
                    acc[mt][nt] = __builtin_amdgcn_mfma_f32_16x16x32_bf16(af[mt], bl, acc[mt][nt], 0,0,0);
                }
            }
        }
    }
    #pragma unroll
    for (int nt = 0; nt < 2; nt++) {
        const int oc = wave*32 + nt*16 + ln;
        const float bias = b2[oc];
        #pragma unroll
        for (int mt = 0; mt < 8; mt++)
            #pragma unroll
            for (int r = 0; r < 4; r++) {
                int pix = mc*128 + mt*16 + quad*4 + r;
                c2b[(f*256 + pix)*128 + oc] = f2b(fmaxf(acc[mt][nt][r] + bias, 0.f));
            }
    }
}

// ============================ conv3 MFMA (bf16, split-B) ============================
// GEMM per (f, ocg): M=64 out-pixels, N=256 oc, K=2048 (16 kk x 128 ic)
__global__ __launch_bounds__(256) void conv3_r13(const u16* __restrict__ c2b,
        const u16* __restrict__ w3h, const u16* __restrict__ w3l,
        const float* __restrict__ b3, float* __restrict__ c3)
{
    __shared__ __align__(16) u16 slab[64*136];   // [pix][128 ic + 8 pad]
    const int f = blockIdx.x, ocg = blockIdx.y, tid = threadIdx.x;
    const int wave = tid >> 6, lane = tid & 63, quad = lane >> 4, ln = lane & 15;
    const int wn = ocg*256 + wave*64;

    f32x4 acc[4][4];
    const f32x4 zz = {0.f, 0.f, 0.f, 0.f};
    #pragma unroll
    for (int mt = 0; mt < 4; mt++)
        #pragma unroll
        for (int nt = 0; nt < 4; nt++) acc[mt][nt] = zz;

    const int sp = tid >> 2;               // staging pixel 0..63
    const int sy = sp >> 3, sx = sp & 7;
    const int sic = (tid & 3) * 32;

    for (int kk = 0; kk < 16; kk++) {
        const int ky = kk >> 2, kx = kk & 3;
        __syncthreads();
        {
            int iy = 2*sy - 1 + ky, ix = 2*sx - 1 + kx;
            uint4* d4 = (uint4*)&slab[sp*136 + sic];
            if (iy >= 0 && iy < 16 && ix >= 0 && ix < 16) {
                const uint4* s4 = (const uint4*)&c2b[((f*16 + iy)*16 + ix)*128 + sic];
                d4[0]=s4[0]; d4[1]=s4[1]; d4[2]=s4[2]; d4[3]=s4[3];
            } else {
                uint4 z = make_uint4(0,0,0,0);
                d4[0]=z; d4[1]=z; d4[2]=z; d4[3]=z;
            }
        }
        __syncthreads();
        #pragma unroll
        for (int ks = 0; ks < 4; ks++) {
            bf16x8 af[4];
            #pragma unroll
            for (int mt = 0; mt < 4; mt++)
                af[mt] = *(const bf16x8*)&slab[(mt*16 + ln)*136 + ks*32 + quad*8];
            #pragma unroll
            for (int nt = 0; nt < 4; nt++) {
                const int oc = wn + nt*16 + ln;
                const int kb = kk*128 + ks*32 + quad*8;
                bf16x8 bh = *(const bf16x8*)&w3h[oc*2048 + kb];
                bf16x8 bl = *(const bf16x8*)&w3l[oc*2048 + kb];
                #pragma unroll
                for (int mt = 0; mt < 4; mt++) {
                    acc[mt][nt] = __builtin_amdgcn_mfma_f32_16x16x32_bf16(af[mt], bh, acc[mt][nt], 0,0,0);
                    acc[mt][nt] = __builtin_amdgcn_mfma_f32_16x16x32_bf16(af[mt], bl, acc[mt][nt], 0,0,0);
                }
            }
        }
    }
    #pragma unroll
    for (int nt = 0; nt < 4; nt++) {
        const int oc = wn + nt*16 + ln;
        const float bias = b3[oc];
        #pragma unroll
        for (int mt = 0; mt < 4; mt++)
            #pragma unroll
            for (int r = 0; r < 4; r++) {
                int pix = mt*16 + quad*4 + r;
                c3[(f*64 + pix)*512 + oc] = fmaxf(acc[mt][nt][r] + bias, 0.f);
            }
    }
}

// ============================ dense -> a_all ============================
__global__ __launch_bounds__(256) void dense_r13(const float* __restrict__ bd,
        float* __restrict__ dout)
{
    const int f = blockIdx.x, tid = threadIdx.x;
    float p0=0,p1=0,p2=0,p3=0,p4=0;
    const float4* x4 = (const float4*)(r13_c3 + f*32768);
    for (int j = tid; j < 8192; j += 256) {
        float4 v = x4[j];
        float4 w0 = *(const float4*)&r13_wdT[          4*j];
        float4 w1 = *(const float4*)&r13_wdT[32768   + 4*j];
        float4 w2 = *(const float4*)&r13_wdT[65536   + 4*j];
        float4 w3 = *(const float4*)&r13_wdT[98304   + 4*j];
        float4 w4 = *(const float4*)&r13_wdT[131072  + 4*j];
        p0 += v.x*w0.x + v.y*w0.y + v.z*w0.z + v.w*w0.w;
        p1 += v.x*w1.x + v.y*w1.y + v.z*w1.z + v.w*w1.w;
        p2 += v.x*w2.x + v.y*w2.y + v.z*w2.z + v.w*w2.w;
        p3 += v.x*w3.x + v.y*w3.y + v.z*w3.z + v.w*w3.w;
        p4 += v.x*w4.x + v.y*w4.y + v.z*w4.z + v.w*w4.w;
    }
    __shared__ float red[5][256];
    red[0][tid]=p0; red[1][tid]=p1; red[2][tid]=p2; red[3][tid]=p3; red[4][tid]=p4;
    __syncthreads();
    for (int st = 128; st > 0; st >>= 1) {
        if (tid < st) {
            #pragma unroll
            for (int d = 0; d < 5; d++) red[d][tid] += red[d][tid+st];
        }
        __syncthreads();
    }
    if (tid < 5) {
        float v = red[tid][0] + bd[tid];
        r13_aall[f*5 + tid] = v;
        dout[OUT_AALL + f*5 + tid] = v;
    }
}

// ============================ LSTM ============================
__global__ __launch_bounds__(128) void lstm_r13(const float* __restrict__ lk,
        const float* __restrict__ lrk, const float* __restrict__ lb)
{
    const int b = blockIdx.x, c = threadIdx.x;
    __shared__ float h[128];
    __shared__ float a[5];
    h[c] = 0.f;
    float cs = 0.f;
    __syncthreads();
    for (int t = 0; t < 128; t++) {
        if (c < 5) a[c] = (t == 0) ? 0.f : r13_aall[(b*128 + (t-1))*5 + c];
        __syncthreads();
        float g[4];
        #pragma unroll
        for (int q = 0; q < 4; q++) {
            int col = q*128 + c;
            float s = lb[col];
            for (int d = 0; d < 5; d++)   s += a[d] * lk[d*512 + col];
            for (int j = 0; j < 128; j++) s += h[j] * lrk[j*512 + col];
            g[q] = s;
        }
        __syncthreads();
        float gi = g[0], gf = g[1], gg = g[2], go = g[3];
        cs = sigm(gf)*cs + sigm(gi)*tanhf(gg);
        float hn = sigm(go)*tanhf(cs);
        h[c] = hn;
        r13_hs[(t*3 + b)*128 + c] = hn;
        __syncthreads();
    }
}

// ============================ abc -> A, C ============================
__global__ __launch_bounds__(192) void abc_r13(const float* __restrict__ wabc,
        const float* __restrict__ babc, float* __restrict__ dout)
{
    const int tb = blockIdx.x, c = threadIdx.x;
    __shared__ float h_lds[128];
    if (c < 128) h_lds[c] = r13_hs[tb*128 + c];
    __syncthreads();
    if (c < 150) {
        float s = babc[c];
        for (int j = 0; j < 128; j++) s += h_lds[j]*wabc[j*150 + c];
        if (c < 100) { r13_A[tb*100 + c] = s; dout[OUT_A + tb*100 + c] = s; }
        else         { r13_C[tb*50 + (c-100)] = s; dout[OUT_C + tb*50 + (c-100)] = s; }
    }
}

// ============================ Kalman filter ============================
__global__ __launch_bounds__(128) void kf_r13(float* __restrict__ dout)
{
    const int b = blockIdx.x, tid = threadIdx.x;
    const int i10 = tid/10, j10 = tid%10;
    __shared__ float A[100], C[50], z[10], P[100], zh[10], AP[100], Ph[100],
                     resid[5], CPm[50], Sa[5][11], PCt[50], K[50], pzv[10], Pn[100], av[5];
    if (tid < 100) P[tid] = (i10==j10) ? 1.f : 0.f;
    if (tid < 10) z[tid] = 0.f;
    for (int t = 0; t < 128; t++) {
        __syncthreads();
        if (tid < 100) A[tid] = r13_A[(t*3+b)*100 + tid];
        if (tid < 50)  C[tid] = r13_C[(t*3+b)*50 + tid];
        if (tid < 5)   av[tid] = r13_aall[(b*128+t)*5 + tid];
        __syncthreads();
        if (tid < 10) { float s=0.f; for (int k=0;k<10;k++) s += A[tid*10+k]*z[k]; zh[tid]=s; }
        if (tid < 100){ float s=0.f; for (int k=0;k<10;k++) s += A[i10*10+k]*P[k*10+j10]; AP[tid]=s; }
        __syncthreads();
        if (tid < 100){ float s=(i10==j10)?0.08f:0.f; for (int k=0;k<10;k++) s += AP[i10*10+k]*A[j10*10+k]; Ph[tid]=s; }
        __syncthreads();
        if (tid < 5)  { float s=av[tid]; for (int k=0;k<10;k++) s -= C[tid*10+k]*zh[k]; resid[tid]=s; }
        if (tid < 50) { int i=tid/10, j=tid%10; float s=0.f; for (int k=0;k<10;k++) s += C[i*10+k]*Ph[k*10+j]; CPm[tid]=s; }
        __syncthreads();
        if (tid < 25) { int i=tid/5, j=tid%5; float s=(i==j)?0.03f:0.f; for (int k=0;k<10;k++) s += CPm[i*10+k]*C[j*10+k]; Sa[i][j]=s; }
        if (tid >= 32 && tid < 57) { int q=tid-32, i=q/5, j=q%5; Sa[i][5+j] = (i==j)?1.f:0.f; }
        if (tid >= 64 && tid < 114){ int q=tid-64, i=q/5, j=q%5; float s=0.f; for (int k=0;k<10;k++) s += Ph[i*10+k]*C[j*10+k]; PCt[q]=s; }
        __syncthreads();
        for (int k = 0; k < 5; k++) {
            const int r = tid/10, cc = tid%10;
            float pinv = 1.f/safed(Sa[k][k]);
            float myf = 0.f, rowv = 0.f;
            if (tid < 50) { myf = Sa[r][k]; rowv = Sa[k][cc]; }
            __syncthreads();
            if (tid < 50) {
                if (r == k) Sa[k][cc] = rowv * pinv;
                else        Sa[r][cc] -= myf * pinv * rowv;
            }
            __syncthreads();
        }
        if (tid < 50) { int i=tid/5, j=tid%5; float s=0.f; for (int k=0;k<5;k++) s += PCt[i*5+k]*Sa[k][5+j]; K[tid]=s; }
        __syncthreads();
        if (tid < 10) { float s=zh[tid]; for (int k=0;k<5;k++) s += K[tid*5+k]*resid[k]; pzv[tid]=s; }
        if (tid < 100){ float s=0.f; for (int k=0;k<5;k++) s += K[i10*5+k]*C[k*10+j10]; AP[tid]=s; }
        __syncthreads();
        if (tid < 100){ float s=Ph[tid]; for (int k=0;k<10;k++) s -= AP[i10*10+k]*Ph[k*10+j10]; Pn[tid]=s; }
        __syncthreads();
        if (tid < 10) { r13_zhat[(t*3+b)*10+tid]=zh[tid]; r13_pz[(t*3+b)*10+tid]=pzv[tid]; z[tid]=pzv[tid]; }
        if (tid < 100){
            float phc = fmaxf(Ph[tid], (i10==j10)?1e-4f:0.f);
            r13_phat[(t*3+b)*100+tid]=phc;
            r13_pp[(t*3+b)*100+tid]=Pn[tid];
            P[tid]=Pn[tid];
        }
    }
    __syncthreads();
    if (tid < 10)  dout[OUT_LASTZ + b*10 + tid]  = z[tid];
    if (tid < 100) dout[OUT_LASTP + b*100 + tid] = P[tid];
}

// ============================ G = A^T @ inv(Phat_clamped) ============================
__global__ __launch_bounds__(256) void ginv_r13()
{
    const int idx = blockIdx.x;
    const int tt = idx/3 + 1, b = idx%3;
    const int tid = threadIdx.x;
    __shared__ float M[10][21];
    __shared__ float A[100];
    __shared__ int piv;
    if (tid < 100) {
        int i = tid/10, j = tid%10;
        M[i][j] = r13_phat[(tt*3+b)*100 + tid];
        M[i][10+j] = (i==j) ? 1.f : 0.f;
        A[tid] = r13_A[(tt*3+b)*100 + tid];
    }
    __syncthreads();
    const int r = tid/20, cc = tid%20;
    for (int k = 0; k < 10; k++) {
        if (tid == 0) {
            int p = k; float best = fabsf(M[k][k]);
            for (int rr = k+1; rr < 10; rr++) {
                float v = fabsf(M[rr][k]);
                if (v > best) { best = v; p = rr; }
            }
            piv = p;
        }
        __syncthreads();
        if (piv != k && tid < 20) {
            float a = M[k][tid], bb = M[piv][tid];
            M[k][tid] = bb; M[piv][tid] = a;
        }
        __syncthreads();
        float pinv = 1.f/safed(M[k][k]);
        float myf = 0.f, rowv = 0.f;
        if (tid < 200) { myf = M[r][k]; rowv = M[k][cc]; }
        __syncthreads();
        if (tid < 200) {
            if (r == k) M[k][cc] = rowv*pinv;
            else        M[r][cc] -= myf*pinv*rowv;
        }
        __syncthreads();
    }
    if (tid < 100) {
        int i = tid/10, j = tid%10;
        float s = 0.f;
        #pragma unroll
        for (int k = 0; k < 10; k++) s += A[k*10+i]*M[k][10+j];
        r13_G[(tt*3+b)*100 + tid] = s;
    }
}

// ============================ RTS smoother ============================
__global__ __launch_bounds__(128) void rts_r13(float* __restrict__ dout)
{
    const int b = blockIdx.x, tid = threadIdx.x;
    const int i10 = tid/10, j10 = tid%10;
    __shared__ float zc[10], Pc[100], D[100], Gt[100], pPm[100], ph[100],
                     zh[10], pzv[10], dz[10], T1[100], zn[10], Pnn[100];
    if (tid < 10)  zc[tid] = r13_pz[(127*3+b)*10 + tid];
    if (tid < 100) Pc[tid] = r13_pp[(127*3+b)*100 + tid];
    for (int t = 126; t >= 0; t--) {
        __syncthreads();
        if (tid < 100) {
            Gt[tid]  = r13_G[((t+1)*3+b)*100 + tid];
            pPm[tid] = r13_pp[(t*3+b)*100 + tid];
            ph[tid]  = r13_phat[((t+1)*3+b)*100 + tid];
        }
        if (tid < 10) {
            zh[tid]  = r13_zhat[((t+1)*3+b)*10 + tid];
            pzv[tid] = r13_pz[(t*3+b)*10 + tid];
        }
        __syncthreads();
        if (tid < 100){ float s=0.f; for (int k=0;k<10;k++) s += pPm[i10*10+k]*Gt[k*10+j10]; D[tid]=s; }
        if (tid < 10) dz[tid] = zc[tid] - zh[tid];
        __syncthreads();
        if (tid < 10) { float s=pzv[tid]; for (int k=0;k<10;k++) s += D[tid*10+k]*dz[k]; zn[tid]=s; }
        if (tid < 100){ float s=0.f; for (int k=0;k<10;k++) s += D[i10*10+k]*(Pc[k*10+j10]-ph[k*10+j10]); T1[tid]=s; }
        __syncthreads();
        if (tid < 100){ float s=pPm[tid]; for (int k=0;k<10;k++) s += T1[i10*10+k]*D[j10*10+k]; Pnn[tid]=s; }
        __syncthreads();
        if (tid < 10) { dout[OUT_ZS + (b*127+t)*10 + tid] = zn[tid]; zc[tid]=zn[tid]; }
        if (tid < 100){ dout[OUT_PS + (b*127+t)*100 + tid] = Pnn[tid]; Pc[tid]=Pnn[tid]; }
    }
}

// ============================ launch ============================
extern "C" void kernel_launch(void* const* d_in, const int* in_sizes, int n_in,
                              void* d_out, int out_size, void* d_ws, size_t ws_size,
                              hipStream_t stream)
{
    (void)in_sizes; (void)n_in; (void)out_size; (void)d_ws; (void)ws_size;
    const float* images = (const float*)d_in[0];
    const float* w1   = (const float*)d_in[1];
    const float* b1   = (const float*)d_in[2];
    const float* w2   = (const float*)d_in[3];
    const float* b2   = (const float*)d_in[4];
    const float* w3   = (const float*)d_in[5];
    const float* b3   = (const float*)d_in[6];
    const float* wd   = (const float*)d_in[7];
    const float* bd   = (const float*)d_in[8];
    const float* lk   = (const float*)d_in[9];
    const float* lrk  = (const float*)d_in[10];
    const float* lb   = (const float*)d_in[11];
    const float* wabc = (const float*)d_in[12];
    const float* babc = (const float*)d_in[13];
    float* dout = (float*)d_out;   // d_out is FLOAT32 (verified R10)

    u16 *c1p, *c2p, *w2hp, *w2lp, *w3hp, *w3lp;
    float *c3p, *wdTp;
    hipGetSymbolAddress((void**)&c1p,  HIP_SYMBOL(r13_c1));
    hipGetSymbolAddress((void**)&c2p,  HIP_SYMBOL(r13_c2));
    hipGetSymbolAddress((void**)&c3p,  HIP_SYMBOL(r13_c3));
    hipGetSymbolAddress((void**)&w2hp, HIP_SYMBOL(r13_w2h));
    hipGetSymbolAddress((void**)&w2lp, HIP_SYMBOL(r13_w2l));
    hipGetSymbolAddress((void**)&w3hp, HIP_SYMBOL(r13_w3h));
    hipGetSymbolAddress((void**)&w3lp, HIP_SYMBOL(r13_w3l));
    hipGetSymbolAddress((void**)&wdTp, HIP_SYMBOL(r13_wdT));

    conv1_r13<<<dim3(384), dim3(256), 0, stream>>>(images, w1, b1, c1p);
    w2t_r13<<<dim3(512), dim3(256), 0, stream>>>(w2, w2hp, w2lp);
    w3t_r13<<<dim3(4096), dim3(256), 0, stream>>>(w3, w3hp, w3lp);
    wdt_r13<<<dim3(640), dim3(256), 0, stream>>>(wd, wdTp);
    conv2_r13<<<dim3(384, 2), dim3(256), 0, stream>>>(c1p, w2hp, w2lp, b2, c2p);
    conv3_r13<<<dim3(384, 2), dim3(256), 0, stream>>>(c2p, w3hp, w3lp, b3, c3p);
    dense_r13<<<dim3(384), dim3(256), 0, stream>>>(bd, dout);
    lstm_r13<<<dim3(3), dim3(128), 0, stream>>>(lk, lrk, lb);
    abc_r13<<<dim3(384), dim3(192), 0, stream>>>(wabc, babc, dout);
    kf_r13<<<dim3(3), dim3(128), 0, stream>>>(dout);
    ginv_r13<<<dim3(381), dim3(256), 0, stream>>>();
    rts_r13<<<dim3(3), dim3(128), 0, stream>>>(dout);
}

// Round 14
// 1147.574 us; speedup vs baseline: 3.6003x; 1.7077x over previous
//
#include <hip/hip_runtime.h>
#include <math.h>

typedef unsigned int   u32;
typedef unsigned short u16;
typedef short bf16x8 __attribute__((ext_vector_type(8)));
typedef float f32x4  __attribute__((ext_vector_type(4)));

// ---- output element offsets (d_out is FLOAT32, 101760 elements) ----
#define OUT_ZS    0
#define OUT_PS    3810
#define OUT_AALL  41910
#define OUT_A     43830
#define OUT_C     82230
#define OUT_LASTZ 101430
#define OUT_LASTP 101460

__device__ __forceinline__ float sigm(float x){ return 1.f/(1.f+expf(-x)); }
__device__ __forceinline__ float safed(float d){
    return (fabsf(d) < 1e-30f) ? ((d < 0.f) ? -1e-30f : 1e-30f) : d;
}
__device__ __forceinline__ u16 f2b(float f) {
    union { float f; u32 u; } v; v.f = f;
    u32 r = v.u + 0x7fffu + ((v.u >> 16) & 1u);   // RNE
    return (u16)(r >> 16);
}
__device__ __forceinline__ float b2f(u16 u) {
    union { u32 x; float f; } v; v.x = ((u32)u) << 16; return v.f;
}
__device__ __forceinline__ u32 packb(float a, float b){ return (u32)f2b(a) | ((u32)f2b(b) << 16); }

// ---- static device workspace ----
__device__ u16   r14_c1[25165824];   // conv1 out bf16 NHWC [384][32][32][64]
__device__ u16   r14_c2[12582912];   // conv2 out bf16 NHWC [384][16][16][128]
__device__ float r14_c3[12582912];   // conv3 out fp32 NHWC [384][8][8][512]
__device__ u16   r14_w2h[131072];    // w2T hi bf16 [128 oc][1024 k]
__device__ u16   r14_w2l[131072];    // w2T lo bf16
__device__ u16   r14_w3h[1048576];   // w3T hi bf16 [512 oc][2048 k]
__device__ u16   r14_w3l[1048576];   // w3T lo bf16
__device__ float r14_wdT[163840];    // [5][32768]
__device__ float r14_hs[49152];
__device__ float r14_zhat[3840];
__device__ float r14_phat[38400];
__device__ float r14_pz[3840];
__device__ float r14_pp[38400];
__device__ float r14_aall[1920];
__device__ float r14_A[38400];
__device__ float r14_C[19200];
__device__ float r14_G[38400];

// ============================ conv1 (fp32 VALU, bf16 NHWC out) ============================
__global__ __launch_bounds__(256) void conv1_r14(const float* __restrict__ img,
        const float* __restrict__ w1, const float* __restrict__ b1, u16* __restrict__ out)
{
    __shared__ float in_lds[66*66];
    const int f = blockIdx.x, tid = threadIdx.x;
    const int og = tid >> 5, sg = tid & 31;

    for (int i = tid; i < 66*66; i += 256) in_lds[i] = 0.f;
    __syncthreads();
    const float4* src = (const float4*)(img + f*4096);
    for (int i = tid; i < 1024; i += 256) {
        int r = i >> 4, c0 = (i & 15) * 4;
        float4 v = src[i];
        float* dst = &in_lds[(r+1)*66 + c0 + 1];
        dst[0]=v.x; dst[1]=v.y; dst[2]=v.z; dst[3]=v.w;
    }
    float wr[16][8];
    #pragma unroll
    for (int k = 0; k < 16; k++) {
        float4 a = *(const float4*)&w1[k*64 + og*8];
        float4 b = *(const float4*)&w1[k*64 + og*8 + 4];
        wr[k][0]=a.x; wr[k][1]=a.y; wr[k][2]=a.z; wr[k][3]=a.w;
        wr[k][4]=b.x; wr[k][5]=b.y; wr[k][6]=b.z; wr[k][7]=b.w;
    }
    float bias[8];
    #pragma unroll
    for (int j = 0; j < 8; j++) bias[j] = b1[og*8+j];
    __syncthreads();

    for (int yy = 0; yy < 32; yy++) {
        float inv[16];
        #pragma unroll
        for (int ky = 0; ky < 4; ky++)
            #pragma unroll
            for (int kx = 0; kx < 4; kx++)
                inv[ky*4+kx] = in_lds[(2*yy+ky)*66 + 2*sg+kx];
        float acc[8];
        #pragma unroll
        for (int j = 0; j < 8; j++) acc[j] = bias[j];
        #pragma unroll
        for (int k = 0; k < 16; k++)
            #pragma unroll
            for (int j = 0; j < 8; j++) acc[j] += inv[k]*wr[k][j];
        #pragma unroll
        for (int j = 0; j < 8; j++) acc[j] = fmaxf(acc[j], 0.f);
        uint4 pk = make_uint4(packb(acc[0],acc[1]), packb(acc[2],acc[3]),
                              packb(acc[4],acc[5]), packb(acc[6],acc[7]));
        *(uint4*)(out + (f*1024 + yy*32 + sg)*64 + og*8) = pk;
    }
}

// ============================ weight transpose + bf16 split ============================
__global__ __launch_bounds__(256) void w2t_r14(const float* __restrict__ w2,
        u16* __restrict__ hi, u16* __restrict__ lo)
{
    int idx = blockIdx.x*256 + threadIdx.x;
    if (idx < 131072) {
        int k = idx >> 7, oc = idx & 127;
        float v = w2[idx];
        u16 h = f2b(v);
        hi[oc*1024 + k] = h;
        lo[oc*1024 + k] = f2b(v - b2f(h));
    }
}
__global__ __launch_bounds__(256) void w3t_r14(const float* __restrict__ w3,
        u16* __restrict__ hi, u16* __restrict__ lo)
{
    int idx = blockIdx.x*256 + threadIdx.x;
    if (idx < 1048576) {
        int k = idx >> 9, oc = idx & 511;
        float v = w3[idx];
        u16 h = f2b(v);
        hi[oc*2048 + k] = h;
        lo[oc*2048 + k] = f2b(v - b2f(h));
    }
}
__global__ __launch_bounds__(256) void wdt_r14(const float* __restrict__ wd, float* __restrict__ wdT)
{
    int idx = blockIdx.x*256 + threadIdx.x;
    if (idx < 163840) {
        int j = idx & 32767, d = idx >> 15;
        wdT[d*32768 + j] = wd[j*20 + d];
    }
}

// ============================ conv2 MFMA (bf16, split-B) ============================
__global__ __launch_bounds__(256) void conv2_r14(const u16* __restrict__ c1b,
        const u16* __restrict__ w2h, const u16* __restrict__ w2l,
        const float* __restrict__ b2, u16* __restrict__ c2b)
{
    __shared__ __align__(16) u16 slab[128*72];
    const int f = blockIdx.x, mc = blockIdx.y, tid = threadIdx.x;
    const int wave = tid >> 6, lane = tid & 63, quad = lane >> 4, ln = lane & 15;

    f32x4 acc[8][2];
    const f32x4 zz = {0.f, 0.f, 0.f, 0.f};
    #pragma unroll
    for (int mt = 0; mt < 8; mt++) { acc[mt][0] = zz; acc[mt][1] = zz; }

    const int sp = tid >> 1;
    const int sy = mc*8 + (sp >> 4), sx = sp & 15;
    const int sic = (tid & 1) * 32;

    for (int kk = 0; kk < 16; kk++) {
        const int ky = kk >> 2, kx = kk & 3;
        __syncthreads();
        {
            int iy = 2*sy - 1 + ky, ix = 2*sx - 1 + kx;
            uint4* d4 = (uint4*)&slab[sp*72 + sic];
            if (iy >= 0 && iy < 32 && ix >= 0 && ix < 32) {
                const uint4* s4 = (const uint4*)&c1b[((f*32 + iy)*32 + ix)*64 + sic];
                d4[0]=s4[0]; d4[1]=s4[1]; d4[2]=s4[2]; d4[3]=s4[3];
            } else {
                uint4 z = make_uint4(0,0,0,0);
                d4[0]=z; d4[1]=z; d4[2]=z; d4[3]=z;
            }
        }
        __syncthreads();
        #pragma unroll
        for (int ks = 0; ks < 2; ks++) {
            bf16x8 af[8];
            #pragma unroll
            for (int mt = 0; mt < 8; mt++)
                af[mt] = *(const bf16x8*)&slab[(mt*16 + ln)*72 + ks*32 + quad*8];
            #pragma unroll
            for (int nt = 0; nt < 2; nt++) {
                const int oc = wave*32 + nt*16 + ln;
                const int kb = kk*64 + ks*32 + quad*8;
                bf16x8 bh = *(const bf16x8*)&w2h[oc*1024 + kb];
                bf16x8 bl = *(const bf16x8*)&w2l[oc*1024 + kb];
                #pragma unroll
                for (int mt = 0; mt < 8; mt++) {
                    acc[mt][nt] = __builtin_amdgcn_mfma_f32_16x16x32_bf16(af[mt], bh, acc[mt][nt], 0,0,0);
                    acc[mt][nt] = __builtin_amdgcn_mfma_f32_16x16x32_bf16(af[mt], bl, acc[mt][nt], 0,0,0);
                }
            }
        }
    }
    #pragma unroll
    for (int nt = 0; nt < 2; nt++) {
        const int oc = wave*32 + nt*16 + ln;
        const float bias = b2[oc];
        #pragma unroll
        for (int mt = 0; mt < 8; mt++)
            #pragma unroll
            for (int r = 0; r < 4; r++) {
                int pix = mc*128 + mt*16 + quad*4 + r;
                c2b[(f*256 + pix)*128 + oc] = f2b(fmaxf(acc[mt][nt][r] + bias, 0.f));
            }
    }
}

// ============================ conv3 MFMA (bf16, split-B) ============================
__global__ __launch_bounds__(256) void conv3_r14(const u16* __restrict__ c2b,
        const u16* __restrict__ w3h, const u16* __restrict__ w3l,
        const float* __restrict__ b3, float* __restrict__ c3)
{
    __shared__ __align__(16) u16 slab[64*136];
    const int f = blockIdx.x, ocg = blockIdx.y, tid = threadIdx.x;
    const int wave = tid >> 6, lane = tid & 63, quad = lane >> 4, ln = lane & 15;
    const int wn = ocg*256 + wave*64;

    f32x4 acc[4][4];
    const f32x4 zz = {0.f, 0.f, 0.f, 0.f};
    #pragma unroll
    for (int mt = 0; mt < 4; mt++)
        #pragma unroll
        for (int nt = 0; nt < 4; nt++) acc[mt][nt] = zz;

    const int sp = tid >> 2;
    const int sy = sp >> 3, sx = sp & 7;
    const int sic = (tid & 3) * 32;

    for (int kk = 0; kk < 16; kk++) {
        const int ky = kk >> 2, kx = kk & 3;
        __syncthreads();
        {
            int iy = 2*sy - 1 + ky, ix = 2*sx - 1 + kx;
            uint4* d4 = (uint4*)&slab[sp*136 + sic];
            if (iy >= 0 && iy < 16 && ix >= 0 && ix < 16) {
                const uint4* s4 = (const uint4*)&c2b[((f*16 + iy)*16 + ix)*128 + sic];
                d4[0]=s4[0]; d4[1]=s4[1]; d4[2]=s4[2]; d4[3]=s4[3];
            } else {
                uint4 z = make_uint4(0,0,0,0);
                d4[0]=z; d4[1]=z; d4[2]=z; d4[3]=z;
            }
        }
        __syncthreads();
        #pragma unroll
        for (int ks = 0; ks < 4; ks++) {
            bf16x8 af[4];
            #pragma unroll
            for (int mt = 0; mt < 4; mt++)
                af[mt] = *(const bf16x8*)&slab[(mt*16 + ln)*136 + ks*32 + quad*8];
            #pragma unroll
            for (int nt = 0; nt < 4; nt++) {
                const int oc = wn + nt*16 + ln;
                const int kb = kk*128 + ks*32 + quad*8;
                bf16x8 bh = *(const bf16x8*)&w3h[oc*2048 + kb];
                bf16x8 bl = *(const bf16x8*)&w3l[oc*2048 + kb];
                #pragma unroll
                for (int mt = 0; mt < 4; mt++) {
                    acc[mt][nt] = __builtin_amdgcn_mfma_f32_16x16x32_bf16(af[mt], bh, acc[mt][nt], 0,0,0);
                    acc[mt][nt] = __builtin_amdgcn_mfma_f32_16x16x32_bf16(af[mt], bl, acc[mt][nt], 0,0,0);
                }
            }
        }
    }
    #pragma unroll
    for (int nt = 0; nt < 4; nt++) {
        const int oc = wn + nt*16 + ln;
        const float bias = b3[oc];
        #pragma unroll
        for (int mt = 0; mt < 4; mt++)
            #pragma unroll
            for (int r = 0; r < 4; r++) {
                int pix = mt*16 + quad*4 + r;
                c3[(f*64 + pix)*512 + oc] = fmaxf(acc[mt][nt][r] + bias, 0.f);
            }
    }
}

// ============================ dense -> a_all ============================
__global__ __launch_bounds__(256) void dense_r14(const float* __restrict__ bd,
        float* __restrict__ dout)
{
    const int f = blockIdx.x, tid = threadIdx.x;
    float p0=0,p1=0,p2=0,p3=0,p4=0;
    const float4* x4 = (const float4*)(r14_c3 + f*32768);
    for (int j = tid; j < 8192; j += 256) {
        float4 v = x4[j];
        float4 w0 = *(const float4*)&r14_wdT[          4*j];
        float4 w1 = *(const float4*)&r14_wdT[32768   + 4*j];
        float4 w2 = *(const float4*)&r14_wdT[65536   + 4*j];
        float4 w3 = *(const float4*)&r14_wdT[98304   + 4*j];
        float4 w4 = *(const float4*)&r14_wdT[131072  + 4*j];
        p0 += v.x*w0.x + v.y*w0.y + v.z*w0.z + v.w*w0.w;
        p1 += v.x*w1.x + v.y*w1.y + v.z*w1.z + v.w*w1.w;
        p2 += v.x*w2.x + v.y*w2.y + v.z*w2.z + v.w*w2.w;
        p3 += v.x*w3.x + v.y*w3.y + v.z*w3.z + v.w*w3.w;
        p4 += v.x*w4.x + v.y*w4.y + v.z*w4.z + v.w*w4.w;
    }
    __shared__ float red[5][256];
    red[0][tid]=p0; red[1][tid]=p1; red[2][tid]=p2; red[3][tid]=p3; red[4][tid]=p4;
    __syncthreads();
    for (int st = 128; st > 0; st >>= 1) {
        if (tid < st) {
            #pragma unroll
            for (int d = 0; d < 5; d++) red[d][tid] += red[d][tid+st];
        }
        __syncthreads();
    }
    if (tid < 5) {
        float v = red[tid][0] + bd[tid];
        r14_aall[f*5 + tid] = v;
        dout[OUT_AALL + f*5 + tid] = v;
    }
}

// ============================ LSTM (512 thr, weights in registers) ============================
__global__ __launch_bounds__(512) void lstm_r14(const float* __restrict__ lk,
        const float* __restrict__ lrk, const float* __restrict__ lb)
{
    const int b = blockIdx.x, c = threadIdx.x;   // c = gate column 0..511
    __shared__ float a_lds[640];
    __shared__ float h_lds[128];
    __shared__ float g_lds[512];
    for (int i = c; i < 640; i += 512) a_lds[i] = r14_aall[b*640 + i];
    if (c < 128) h_lds[c] = 0.f;
    float wreg[128];                    // lrk column resident in VGPRs
    #pragma unroll
    for (int j = 0; j < 128; j++) wreg[j] = lrk[j*512 + c];
    float lkr[5];
    #pragma unroll
    for (int d = 0; d < 5; d++) lkr[d] = lk[d*512 + c];
    const float gb = lb[c];
    float cs = 0.f;
    __syncthreads();
    for (int t = 0; t < 128; t++) {
        float g = gb;
        if (t > 0) {
            #pragma unroll
            for (int d = 0; d < 5; d++) g += a_lds[(t-1)*5 + d] * lkr[d];
        }
        float s0=0.f, s1=0.f, s2=0.f, s3=0.f;   // 4 chains to break fp-add dependence
        #pragma unroll
        for (int j = 0; j < 128; j += 4) {
            float4 h4 = *(const float4*)&h_lds[j];
            s0 += h4.x*wreg[j];   s1 += h4.y*wreg[j+1];
            s2 += h4.z*wreg[j+2]; s3 += h4.w*wreg[j+3];
        }
        g += (s0 + s1) + (s2 + s3);
        g_lds[c] = g;
        __syncthreads();
        if (c < 128) {
            float gi = g_lds[c], gf = g_lds[c+128], gg = g_lds[c+256], go = g_lds[c+384];
            cs = sigm(gf)*cs + sigm(gi)*tanhf(gg);
            float hn = sigm(go)*tanhf(cs);
            h_lds[c] = hn;
            r14_hs[(t*3 + b)*128 + c] = hn;
        }
        __syncthreads();
    }
}

// ============================ abc -> A, C ============================
__global__ __launch_bounds__(192) void abc_r14(const float* __restrict__ wabc,
        const float* __restrict__ babc, float* __restrict__ dout)
{
    const int tb = blockIdx.x, c = threadIdx.x;
    __shared__ float h_lds[128];
    if (c < 128) h_lds[c] = r14_hs[tb*128 + c];
    __syncthreads();
    if (c < 150) {
        float s = babc[c];
        for (int j = 0; j < 128; j++) s += h_lds[j]*wabc[j*150 + c];
        if (c < 100) { r14_A[tb*100 + c] = s; dout[OUT_A + tb*100 + c] = s; }
        else         { r14_C[tb*50 + (c-100)] = s; dout[OUT_C + tb*50 + (c-100)] = s; }
    }
}

// ============================ Kalman filter ============================
__global__ __launch_bounds__(128) void kf_r14(float* __restrict__ dout)
{
    const int b = blockIdx.x, tid = threadIdx.x;
    const int i10 = tid/10, j10 = tid%10;
    __shared__ float A[100], C[50], z[10], P[100], zh[10], AP[100], Ph[100],
                     resid[5], CPm[50], Sa[5][11], PCt[50], K[50], pzv[10], Pn[100], av[5];
    if (tid < 100) P[tid] = (i10==j10) ? 1.f : 0.f;
    if (tid < 10) z[tid] = 0.f;
    for (int t = 0; t < 128; t++) {
        __syncthreads();
        if (tid < 100) A[tid] = r14_A[(t*3+b)*100 + tid];
        if (tid < 50)  C[tid] = r14_C[(t*3+b)*50 + tid];
        if (tid < 5)   av[tid] = r14_aall[(b*128+t)*5 + tid];
        __syncthreads();
        if (tid < 10) { float s=0.f; for (int k=0;k<10;k++) s += A[tid*10+k]*z[k]; zh[tid]=s; }
        if (tid < 100){ float s=0.f; for (int k=0;k<10;k++) s += A[i10*10+k]*P[k*10+j10]; AP[tid]=s; }
        __syncthreads();
        if (tid < 100){ float s=(i10==j10)?0.08f:0.f; for (int k=0;k<10;k++) s += AP[i10*10+k]*A[j10*10+k]; Ph[tid]=s; }
        __syncthreads();
        if (tid < 5)  { float s=av[tid]; for (int k=0;k<10;k++) s -= C[tid*10+k]*zh[k]; resid[tid]=s; }
        if (tid < 50) { int i=tid/10, j=tid%10; float s=0.f; for (int k=0;k<10;k++) s += C[i*10+k]*Ph[k*10+j]; CPm[tid]=s; }
        __syncthreads();
        if (tid < 25) { int i=tid/5, j=tid%5; float s=(i==j)?0.03f:0.f; for (int k=0;k<10;k++) s += CPm[i*10+k]*C[j*10+k]; Sa[i][j]=s; }
        if (tid >= 32 && tid < 57) { int q=tid-32, i=q/5, j=q%5; Sa[i][5+j] = (i==j)?1.f:0.f; }
        if (tid >= 64 && tid < 114){ int q=tid-64, i=q/5, j=q%5; float s=0.f; for (int k=0;k<10;k++) s += Ph[i*10+k]*C[j*10+k]; PCt[q]=s; }
        __syncthreads();
        for (int k = 0; k < 5; k++) {
            const int r = tid/10, cc = tid%10;
            float pinv = 1.f/safed(Sa[k][k]);
            float myf = 0.f, rowv = 0.f;
            if (tid < 50) { myf = Sa[r][k]; rowv = Sa[k][cc]; }
            __syncthreads();
            if (tid < 50) {
                if (r == k) Sa[k][cc] = rowv * pinv;
                else        Sa[r][cc] -= myf * pinv * rowv;
            }
            __syncthreads();
        }
        if (tid < 50) { int i=tid/5, j=tid%5; float s=0.f; for (int k=0;k<5;k++) s += PCt[i*5+k]*Sa[k][5+j]; K[tid]=s; }
        __syncthreads();
        if (tid < 10) { float s=zh[tid]; for (int k=0;k<5;k++) s += K[tid*5+k]*resid[k]; pzv[tid]=s; }
        if (tid < 100){ float s=0.f; for (int k=0;k<5;k++) s += K[i10*5+k]*C[k*10+j10]; AP[tid]=s; }
        __syncthreads();
        if (tid < 100){ float s=Ph[tid]; for (int k=0;k<10;k++) s -= AP[i10*10+k]*Ph[k*10+j10]; Pn[tid]=s; }
        __syncthreads();
        if (tid < 10) { r14_zhat[(t*3+b)*10+tid]=zh[tid]; r14_pz[(t*3+b)*10+tid]=pzv[tid]; z[tid]=pzv[tid]; }
        if (tid < 100){
            float phc = fmaxf(Ph[tid], (i10==j10)?1e-4f:0.f);
            r14_phat[(t*3+b)*100+tid]=phc;
            r14_pp[(t*3+b)*100+tid]=Pn[tid];
            P[tid]=Pn[tid];
        }
    }
    __syncthreads();
    if (tid < 10)  dout[OUT_LASTZ + b*10 + tid]  = z[tid];
    if (tid < 100) dout[OUT_LASTP + b*100 + tid] = P[tid];
}

// ============================ G = A^T @ inv(Phat_clamped) ============================
__global__ __launch_bounds__(256) void ginv_r14()
{
    const int idx = blockIdx.x;
    const int tt = idx/3 + 1, b = idx%3;
    const int tid = threadIdx.x;
    __shared__ float M[10][21];
    __shared__ float A[100];
    __shared__ int piv;
    if (tid < 100) {
        int i = tid/10, j = tid%10;
        M[i][j] = r14_phat[(tt*3+b)*100 + tid];
        M[i][10+j] = (i==j) ? 1.f : 0.f;
        A[tid] = r14_A[(tt*3+b)*100 + tid];
    }
    __syncthreads();
    const int r = tid/20, cc = tid%20;
    for (int k = 0; k < 10; k++) {
        if (tid == 0) {
            int p = k; float best = fabsf(M[k][k]);
            for (int rr = k+1; rr < 10; rr++) {
                float v = fabsf(M[rr][k]);
                if (v > best) { best = v; p = rr; }
            }
            piv = p;
        }
        __syncthreads();
        if (piv != k && tid < 20) {
            float a = M[k][tid], bb = M[piv][tid];
            M[k][tid] = bb; M[piv][tid] = a;
        }
        __syncthreads();
        float pinv = 1.f/safed(M[k][k]);
        float myf = 0.f, rowv = 0.f;
        if (tid < 200) { myf = M[r][k]; rowv = M[k][cc]; }
        __syncthreads();
        if (tid < 200) {
            if (r == k) M[k][cc] = rowv*pinv;
            else        M[r][cc] -= myf*pinv*rowv;
        }
        __syncthreads();
    }
    if (tid < 100) {
        int i = tid/10, j = tid%10;
        float s = 0.f;
        #pragma unroll
        for (int k = 0; k < 10; k++) s += A[k*10+i]*M[k][10+j];
        r14_G[(tt*3+b)*100 + tid] = s;
    }
}

// ============================ RTS smoother ============================
__global__ __launch_bounds__(128) void rts_r14(float* __restrict__ dout)
{
    const int b = blockIdx.x, tid = threadIdx.x;
    const int i10 = tid/10, j10 = tid%10;
    __shared__ float zc[10], Pc[100], D[100], Gt[100], pPm[100], ph[100],
                     zh[10], pzv[10], dz[10], T1[100], zn[10], Pnn[100];
    if (tid < 10)  zc[tid] = r14_pz[(127*3+b)*10 + tid];
    if (tid < 100) Pc[tid] = r14_pp[(127*3+b)*100 + tid];
    for (int t = 126; t >= 0; t--) {
        __syncthreads();
        if (tid < 100) {
            Gt[tid]  = r14_G[((t+1)*3+b)*100 + tid];
            pPm[tid] = r14_pp[(t*3+b)*100 + tid];
            ph[tid]  = r14_phat[((t+1)*3+b)*100 + tid];
        }
        if (tid < 10) {
            zh[tid]  = r14_zhat[((t+1)*3+b)*10 + tid];
            pzv[tid] = r14_pz[(t*3+b)*10 + tid];
        }
        __syncthreads();
        if (tid < 100){ float s=0.f; for (int k=0;k<10;k++) s += pPm[i10*10+k]*Gt[k*10+j10]; D[tid]=s; }
        if (tid < 10) dz[tid] = zc[tid] - zh[tid];
        __syncthreads();
        if (tid < 10) { float s=pzv[tid]; for (int k=0;k<10;k++) s += D[tid*10+k]*dz[k]; zn[tid]=s; }
        if (tid < 100){ float s=0.f; for (int k=0;k<10;k++) s += D[i10*10+k]*(Pc[k*10+j10]-ph[k*10+j10]); T1[tid]=s; }
        __syncthreads();
        if (tid < 100){ float s=pPm[tid]; for (int k=0;k<10;k++) s += T1[i10*10+k]*D[j10*10+k]; Pnn[tid]=s; }
        __syncthreads();
        if (tid < 10) { dout[OUT_ZS + (b*127+t)*10 + tid] = zn[tid]; zc[tid]=zn[tid]; }
        if (tid < 100){ dout[OUT_PS + (b*127+t)*100 + tid] = Pnn[tid]; Pc[tid]=Pnn[tid]; }
    }
}

// ============================ launch ============================
extern "C" void kernel_launch(void* const* d_in, const int* in_sizes, int n_in,
                              void* d_out, int out_size, void* d_ws, size_t ws_size,
                              hipStream_t stream)
{
    (void)in_sizes; (void)n_in; (void)out_size; (void)d_ws; (void)ws_size;
    const float* images = (const float*)d_in[0];
    const float* w1   = (const float*)d_in[1];
    const float* b1   = (const float*)d_in[2];
    const float* w2   = (const float*)d_in[3];
    const float* b2   = (const float*)d_in[4];
    const float* w3   = (const float*)d_in[5];
    const float* b3   = (const float*)d_in[6];
    const float* wd   = (const float*)d_in[7];
    const float* bd   = (const float*)d_in[8];
    const float* lk   = (const float*)d_in[9];
    const float* lrk  = (const float*)d_in[10];
    const float* lb   = (const float*)d_in[11];
    const float* wabc = (const float*)d_in[12];
    const float* babc = (const float*)d_in[13];
    float* dout = (float*)d_out;   // d_out is FLOAT32 (verified R10)

    u16 *c1p, *c2p, *w2hp, *w2lp, *w3hp, *w3lp;
    float *c3p, *wdTp;
    hipGetSymbolAddress((void**)&c1p,  HIP_SYMBOL(r14_c1));
    hipGetSymbolAddress((void**)&c2p,  HIP_SYMBOL(r14_c2));
    hipGetSymbolAddress((void**)&c3p,  HIP_SYMBOL(r14_c3));
    hipGetSymbolAddress((void**)&w2hp, HIP_SYMBOL(r14_w2h));
    hipGetSymbolAddress((void**)&w2lp, HIP_SYMBOL(r14_w2l));
    hipGetSymbolAddress((void**)&w3hp, HIP_SYMBOL(r14_w3h));
    hipGetSymbolAddress((void**)&w3lp, HIP_SYMBOL(r14_w3l));
    hipGetSymbolAddress((void**)&wdTp, HIP_SYMBOL(r14_wdT));

    conv1_r14<<<dim3(384), dim3(256), 0, stream>>>(images, w1, b1, c1p);
    w2t_r14<<<dim3(512), dim3(256), 0, stream>>>(w2, w2hp, w2lp);
    w3t_r14<<<dim3(4096), dim3(256), 0, stream>>>(w3, w3hp, w3lp);
    wdt_r14<<<dim3(640), dim3(256), 0, stream>>>(wd, wdTp);
    conv2_r14<<<dim3(384, 2), dim3(256), 0, stream>>>(c1p, w2hp, w2lp, b2, c2p);
    conv3_r14<<<dim3(384, 2), dim3(256), 0, stream>>>(c2p, w3hp, w3lp, b3, c3p);
    dense_r14<<<dim3(384), dim3(256), 0, stream>>>(bd, dout);
    lstm_r14<<<dim3(3), dim3(512), 0, stream>>>(lk, lrk, lb);
    abc_r14<<<dim3(384), dim3(192), 0, stream>>>(wabc, babc, dout);
    kf_r14<<<dim3(3), dim3(128), 0, stream>>>(dout);
    ginv_r14<<<dim3(381), dim3(256), 0, stream>>>();
    rts_r14<<<dim3(3), dim3(128), 0, stream>>>(dout);
}